// Round 13
// baseline (70.046 us; speedup 1.0000x reference)
//
#include <hip/hip_runtime.h>
#include <math.h>

#define B_    16
#define N_    6
#define P_    70000
#define H_    112
#define W_    200
#define HW_   (H_ * W_)
#define BSN_  (B_ * N_)
#define HALF_ 56
#define CELLS_ (HALF_ * W_)            // 11200 cells, 44.8 KB LDS

// K1 geometry: one point per thread. 16 x 69 blocks x 1024 threads.
#define K1T   1024
#define K1BLK 69                       // ceil(70000/1024)
#define K1CAP (K1T * N_)               // 6144 worst-case entries per block

// ws: matrices | counts[16*69] | entries[16*69][K1CAP] u32  (~27.2 MB)
#define WS_MAT_OFF 0                   // floats: Vinv 16x12 | PFC 96x12 | E2 96x4
#define WS_PFC   192
#define WS_E2    1344
#define WS_CNT_OFF 8192
#define WS_ENT_OFF 16384
#define WS_NEED (WS_ENT_OFF + (size_t)B_ * K1BLK * K1CAP * 4)

// ---------- shared math helpers (identical codegen everywhere) ----------

__device__ __forceinline__ float rdot4(float r0, float r1, float r2, float r3,
                                       float x, float y, float z) {
    float s = r0 * x;
    s = fmaf(r1, y, s);
    s = fmaf(r2, z, s);
    return s + r3;
}

// 4x4 inverse via adjugate (matches jnp.linalg.inv bit-for-bit here — absmax
// 0.0 through rounds 1-12)
__device__ __forceinline__ void inv4(const float* m, float* o) {
    float inv[16];
    inv[0]  =  m[5]*m[10]*m[15] - m[5]*m[11]*m[14] - m[9]*m[6]*m[15] + m[9]*m[7]*m[14] + m[13]*m[6]*m[11] - m[13]*m[7]*m[10];
    inv[4]  = -m[4]*m[10]*m[15] + m[4]*m[11]*m[14] + m[8]*m[6]*m[15] - m[8]*m[7]*m[14] - m[12]*m[6]*m[11] + m[12]*m[7]*m[10];
    inv[8]  =  m[4]*m[9]*m[15]  - m[4]*m[11]*m[13] - m[8]*m[5]*m[15] + m[8]*m[7]*m[13] + m[12]*m[5]*m[11] - m[12]*m[7]*m[9];
    inv[12] = -m[4]*m[9]*m[14]  + m[4]*m[10]*m[13] + m[8]*m[5]*m[14] - m[8]*m[6]*m[13] - m[12]*m[5]*m[10] + m[12]*m[6]*m[9];
    inv[1]  = -m[1]*m[10]*m[15] + m[1]*m[11]*m[14] + m[9]*m[2]*m[15] - m[9]*m[3]*m[14] - m[13]*m[2]*m[11] + m[13]*m[3]*m[10];
    inv[5]  =  m[0]*m[10]*m[15] - m[0]*m[11]*m[14] - m[8]*m[2]*m[15] + m[8]*m[3]*m[14] + m[12]*m[2]*m[11] - m[12]*m[3]*m[10];
    inv[9]  = -m[0]*m[9]*m[15]  + m[0]*m[11]*m[13] + m[8]*m[1]*m[15] - m[8]*m[3]*m[13] - m[12]*m[1]*m[11] + m[12]*m[3]*m[9];
    inv[13] =  m[0]*m[9]*m[14]  - m[0]*m[10]*m[13] - m[8]*m[1]*m[14] + m[8]*m[2]*m[13] + m[12]*m[1]*m[10] - m[12]*m[2]*m[9];
    inv[2]  =  m[1]*m[6]*m[15]  - m[1]*m[7]*m[14]  - m[5]*m[2]*m[15] + m[5]*m[3]*m[14] + m[13]*m[2]*m[7]  - m[13]*m[3]*m[6];
    inv[6]  = -m[0]*m[6]*m[15]  + m[0]*m[7]*m[14]  + m[4]*m[2]*m[15] - m[4]*m[3]*m[14] - m[12]*m[2]*m[7]  + m[12]*m[3]*m[6];
    inv[10] =  m[0]*m[5]*m[15]  - m[0]*m[7]*m[13]  - m[4]*m[1]*m[15] + m[4]*m[3]*m[13] + m[12]*m[1]*m[7]  - m[12]*m[3]*m[5];
    inv[14] = -m[0]*m[5]*m[14]  + m[0]*m[6]*m[13]  + m[4]*m[1]*m[14] - m[4]*m[2]*m[13] - m[12]*m[1]*m[6]  + m[12]*m[2]*m[5];
    inv[3]  = -m[1]*m[6]*m[11]  + m[1]*m[7]*m[10]  + m[5]*m[2]*m[11] - m[5]*m[3]*m[10] - m[9]*m[2]*m[7]   + m[9]*m[3]*m[6];
    inv[7]  =  m[0]*m[6]*m[11]  - m[0]*m[7]*m[10]  - m[4]*m[2]*m[11] + m[4]*m[3]*m[10] + m[8]*m[2]*m[7]   - m[8]*m[3]*m[6];
    inv[11] = -m[0]*m[5]*m[11]  + m[0]*m[7]*m[9]   + m[4]*m[1]*m[11] - m[4]*m[3]*m[9]  - m[8]*m[1]*m[7]   + m[8]*m[3]*m[5];
    inv[15] =  m[0]*m[5]*m[10]  - m[0]*m[6]*m[9]   - m[4]*m[1]*m[10] + m[4]*m[2]*m[9]  + m[8]*m[1]*m[6]   - m[8]*m[2]*m[5];
    float det = m[0]*inv[0] + m[1]*inv[4] + m[2]*inv[8] + m[3]*inv[12];
    float rdet = 1.0f / det;
    for (int i = 0; i < 16; ++i) o[i] = inv[i] * rdet;
}

// Per-camera: Einv (rigid inverse) and PFC = scale_intrinsics4(K) @ Einv.
__device__ __forceinline__ void cam_mats(const float* Ein, const float* Kin,
                                         float E2[4], float PFC[3][4]) {
    float Einv[4][4];
    for (int i = 0; i < 3; ++i)
        for (int j = 0; j < 3; ++j)
            Einv[i][j] = Ein[j * 4 + i];          // R^T
    for (int i = 0; i < 3; ++i) {                  // -(R^T t), asc-j fma
        float s = Ein[0 * 4 + i] * Ein[0 * 4 + 3];
        s = fmaf(Ein[1 * 4 + i], Ein[1 * 4 + 3], s);
        s = fmaf(Ein[2 * 4 + i], Ein[2 * 4 + 3], s);
        Einv[i][3] = -s;
    }
    Einv[3][0] = Ein[12]; Einv[3][1] = Ein[13];
    Einv[3][2] = Ein[14]; Einv[3][3] = Ein[15];

    float K4[4][4] = {};
    K4[0][0] = Kin[0] * 0.25f;  K4[0][2] = Kin[2] * 0.25f;
    K4[1][1] = Kin[4] * 0.25f;  K4[1][2] = Kin[5] * 0.25f;
    K4[2][2] = 1.0f;            K4[3][3] = 1.0f;

    for (int i = 0; i < 3; ++i)
        for (int j = 0; j < 4; ++j) {
            float s = K4[i][0] * Einv[0][j];
            s = fmaf(K4[i][1], Einv[1][j], s);
            s = fmaf(K4[i][2], Einv[2][j], s);
            s = fmaf(K4[i][3], Einv[3][j], s);
            PFC[i][j] = s;
        }
    for (int j = 0; j < 4; ++j) E2[j] = Einv[2][j];
}

// ---------- K0: all matrices once -> ws (global, s_load-able) ----------

__global__ __launch_bounds__(128) void k_mats(
        const float* __restrict__ extr, const float* __restrict__ intr,
        const float* __restrict__ view, float* __restrict__ wsf) {
    const int t = threadIdx.x;
    if (t < BSN_) {
        float E2[4], PFC[3][4];
        cam_mats(&extr[t * 16], &intr[t * 9], E2, PFC);
        for (int i = 0; i < 3; ++i)
            for (int j = 0; j < 4; ++j) wsf[WS_PFC + t * 12 + i * 4 + j] = PFC[i][j];
        for (int j = 0; j < 4; ++j) wsf[WS_E2 + t * 4 + j] = E2[j];
    } else if (t < BSN_ + B_) {
        int b = t - BSN_;
        float Vi[16];
        inv4(&view[b * 16], Vi);
        for (int k = 0; k < 12; ++k) wsf[b * 12 + k] = Vi[k];
    }
}

// ---------- K1: one point per thread; screens only; rare -> ws segment ----
// Corner certainty via conservative screens on the EXACT px,py,denom:
//   px <= 0.99*denom => x_ < 1 => xm==0 ;  px >= 201*denom => x_ > 200.9 => xm==199
//   py <= 0.99*denom => ym==0 ;  py >= 113*denom => y_ > 112.9 => ym==111
// (fp32 rounding << margins, implication exact.) Uncertain (cam,p) pairs go
// to this block's ws segment; K2 replays the exact reference sequence.

__global__ __launch_bounds__(K1T) void k_classify(
        const float4* __restrict__ pc, const float* __restrict__ wsf,
        int* __restrict__ counts, unsigned int* __restrict__ entries) {
    __shared__ int scnt;
    const int b     = blockIdx.x;
    const int chunk = blockIdx.y;
    const int t     = threadIdx.x;
    if (t == 0) scnt = 0;
    __syncthreads();

    const int p   = chunk * K1T + t;
    const int seg = b * K1BLK + chunk;
    const bool valid = (p < P_);
    float4 pt = make_float4(0.f, 0.f, 0.f, 0.f);
    if (valid) pt = pc[(size_t)b * P_ + p];

    const float* V = wsf + b * 12;       // wave-uniform -> scalar loads
    float lx = rdot4(V[0], V[1], V[2],  V[3],  pt.x, pt.y, pt.z);
    float ly = rdot4(V[4], V[5], V[6],  V[7],  pt.x, pt.y, pt.z);
    float lz = rdot4(V[8], V[9], V[10], V[11], pt.x, pt.y, pt.z);

    unsigned rfl = 0;
    #pragma unroll
    for (int n = 0; n < 6; ++n) {
        const float* Pm = wsf + WS_PFC + (b * N_ + n) * 12;   // uniform
        float px = rdot4(Pm[0], Pm[1], Pm[2],  Pm[3],  lx, ly, lz);
        float py = rdot4(Pm[4], Pm[5], Pm[6],  Pm[7],  lx, ly, lz);
        float pz = rdot4(Pm[8], Pm[9], Pm[10], Pm[11], lx, ly, lz);
        float denom = fmaxf(pz, 1e-6f);
        bool x0 = (px <= 0.99f * denom), x1 = (px >= 201.0f * denom);
        bool y0 = (py <= 0.99f * denom), y1 = (py >= 113.0f * denom);
        if (!((x0 | x1) & (y0 | y1))) rfl |= (1u << n);
    }
    if (valid && rfl) {
        unsigned int* ent = entries + (size_t)seg * K1CAP;
        #pragma unroll
        for (int n = 0; n < 6; ++n)
            if (rfl & (1u << n)) {
                int pos = atomicAdd(&scnt, 1);
                ent[pos] = ((unsigned)n << 17) | (unsigned)p;
            }
    }
    __syncthreads();
    if (t == 0) counts[seg] = scnt;
}

// ---------- K2: corner back-scan + rare merge + finalize. Block=(cam,half) --

__global__ __launch_bounds__(1024) void k_fin2(
        const float4* __restrict__ pc, const float* __restrict__ wsf,
        const int* __restrict__ counts, const unsigned int* __restrict__ entries,
        float* __restrict__ out, const int* __restrict__ bev_side_p) {
    __shared__ int   win[CELLS_];      // 44.8 KB
    __shared__ float sM[28];           // 0..11 Vinv, 12..23 PFC, 24..27 E2
    __shared__ int   cw[2];            // certain corner winners (in-half)

    const int i    = blockIdx.x;       // 0..191, XCD swizzle matches K1 (b%8)
    const int xcd  = i & 7;
    const int s    = i >> 3;
    const int b    = xcd + 8 * (s >= 12 ? 1 : 0);
    const int c12  = s % 12;
    const int cam  = c12 >> 1;
    const int half = c12 & 1;
    const int m    = b * N_ + cam;
    const int rlo  = half * HALF_;
    const int t    = threadIdx.x;
    const int lane = t & 63;
    const int w    = t >> 6;

    if (t == 0) {
        for (int k = 0; k < 12; ++k) sM[k] = wsf[b * 12 + k];
        cw[0] = -1; cw[1] = -1;
    } else if (t == 64) {
        for (int k = 0; k < 12; ++k) sM[12 + k] = wsf[WS_PFC + m * 12 + k];
        for (int k = 0; k < 4; ++k)  sM[24 + k] = wsf[WS_E2 + m * 4 + k];
    }
    for (int k = t; k < CELLS_; k += 1024) win[k] = -1;
    __syncthreads();

    const float V0 = sM[0],  V1 = sM[1],  V2 = sM[2],  V3 = sM[3];
    const float V4 = sM[4],  V5 = sM[5],  V6 = sM[6],  V7 = sM[7];
    const float V8 = sM[8],  V9 = sM[9],  V10 = sM[10], V11 = sM[11];
    const float P00 = sM[12], P01 = sM[13], P02 = sM[14], P03 = sM[15];
    const float P10 = sM[16], P11 = sM[17], P12 = sM[18], P13 = sM[19];
    const float P20 = sM[20], P21 = sM[21], P22 = sM[22], P23 = sM[23];
    const float4* pcb = pc + (size_t)b * P_;

    // ---- corner back-scan: topmost chunk with a certain hit gives max p ----
    for (int cbase = (K1BLK - 1) * K1T; cbase >= 0; cbase -= K1T) {
        int p = cbase + t;
        bool valid = (p < P_);
        float4 pt = make_float4(0.f, 0.f, 0.f, 0.f);
        if (valid) pt = pcb[p];
        float lx = rdot4(V0, V1, V2,  V3,  pt.x, pt.y, pt.z);
        float ly = rdot4(V4, V5, V6,  V7,  pt.x, pt.y, pt.z);
        float lz = rdot4(V8, V9, V10, V11, pt.x, pt.y, pt.z);
        float px = rdot4(P00, P01, P02, P03, lx, ly, lz);
        float py = rdot4(P10, P11, P12, P13, lx, ly, lz);
        float pz = rdot4(P20, P21, P22, P23, lx, ly, lz);
        float denom = fmaxf(pz, 1e-6f);
        bool x0 = (px <= 0.99f * denom), x1 = (px >= 201.0f * denom);
        bool y0 = (py <= 0.99f * denom), y1 = (py >= 113.0f * denom);
        bool certA, certB;
        if (half == 0) { certA = x0 & y0; certB = x1 & y0; }   // (0,0) (0,199)
        else           { certA = x0 & y1; certB = x1 & y1; }   // (111,0) (111,199)
        unsigned long long mA = __ballot(valid && certA);
        unsigned long long mB = __ballot(valid && certB);
        if (lane == 0) {
            if (mA) atomicMax(&cw[0], cbase + (w << 6) + 63 - __builtin_clzll(mA));
            if (mB) atomicMax(&cw[1], cbase + (w << 6) + 63 - __builtin_clzll(mB));
        }
        __syncthreads();
        int a0 = cw[0], a1 = cw[1];
        __syncthreads();
        if (a0 >= 0 && a1 >= 0) break;
    }

    // ---- rare merge: segments distributed across 16 waves ----
    for (int s2 = w; s2 < K1BLK; s2 += 16) {
        const int seg = b * K1BLK + s2;
        const int cnt = counts[seg];
        const unsigned int* ent = entries + (size_t)seg * K1CAP;
        for (int e = lane; e < cnt; e += 64) {
            unsigned int v = ent[e];
            if ((int)(v >> 17) == cam) {
                int p = (int)(v & 0x1FFFFu);
                float4 pt = pcb[p];
                float lx = rdot4(V0, V1, V2,  V3,  pt.x, pt.y, pt.z);
                float ly = rdot4(V4, V5, V6,  V7,  pt.x, pt.y, pt.z);
                float lz = rdot4(V8, V9, V10, V11, pt.x, pt.y, pt.z);
                float px = rdot4(P00, P01, P02, P03, lx, ly, lz);
                float py = rdot4(P10, P11, P12, P13, lx, ly, lz);
                float pz = rdot4(P20, P21, P22, P23, lx, ly, lz);
                float denom = fmaxf(pz, 1e-6f);
                float x_ = px / denom;            // exact reference sequence
                float y_ = py / denom;
                int ym = (int)fminf(fmaxf(y_, 0.0f), (float)(H_ - 1));
                int xm = (int)fminf(fmaxf(x_, 0.0f), (float)(W_ - 1));
                int rr = ym - rlo;
                if ((unsigned)rr < (unsigned)HALF_)
                    atomicMax(&win[rr * W_ + xm], p);
            }
        }
    }
    // corner inject (merges with any rare hits on the corner cells)
    if (t == 0) {
        int cell0 = half ? (HALF_ - 1) * W_ : 0;
        if (cw[0] >= 0) atomicMax(&win[cell0],          cw[0]);
        if (cw[1] >= 0) atomicMax(&win[cell0 + W_ - 1], cw[1]);
    }
    __syncthreads();

    // ---- finalize (bit-exact path, proven rounds 1-12) ----
    const float bev_half = (float)bev_side_p[0] * 0.5f;   // 100.0
    const float clip_hi  = bev_half - 1.0f;               // 99.0
    const float E20 = sM[24], E21 = sM[25], E22 = sM[26], E23 = sM[27];
    const int base0 = (m * 2) * HW_ + rlo * W_;
    for (int rr = t; rr < CELLS_; rr += 1024) {
        int wv = win[rr];
        float depth = 0.0f, iluv = 0.0f;
        if (wv >= 0) {
            float4 pt = pcb[wv];
            float lx = rdot4(V0, V1, V2,  V3,  pt.x, pt.y, pt.z);
            float ly = rdot4(V4, V5, V6,  V7,  pt.x, pt.y, pt.z);
            float lz = rdot4(V8, V9, V10, V11, pt.x, pt.y, pt.z);
            float z  = rdot4(E20, E21, E22, E23, lx, ly, lz);
            float px = rdot4(P00, P01, P02, P03, lx, ly, lz);
            float py = rdot4(P10, P11, P12, P13, lx, ly, lz);
            float pz = rdot4(P20, P21, P22, P23, lx, ly, lz);
            float denom = fmaxf(pz, 1e-6f);
            float x_ = px / denom;
            float y_ = py / denom;
            bool valid = (x_ > -0.5f) && (x_ < (float)W_ - 0.5f) &&
                         (y_ > -0.5f) && (y_ < (float)H_ - 0.5f) && (z > 0.0f);
            if (valid) {
                float d = fminf(fmaxf(pz, 0.0f), clip_hi);     // clip(normalizer,0,99)
                depth = d / bev_half;                           // /100
                float vi = fminf(fmaxf(pt.w, 0.0f), 255.0f);    // clip(ilu,0,255)
                iluv = log1pf(vi) / 5.545177444479562f;         // /log(256) as f32
            }
        }
        out[base0 + rr]       = depth;
        out[base0 + HW_ + rr] = iluv;
    }
}

// ---------- fallback (R8 single-kernel path, if ws too small) ----------

#define PMAIN 69632
#define PTAIL (P_ - PMAIN)

__global__ __launch_bounds__(1024, 4) void k_lidar_ilp(
        const float4* __restrict__ pc, const float* __restrict__ extr,
        const float* __restrict__ intr, const float* __restrict__ view,
        float* __restrict__ out, const int* __restrict__ bev_side_p) {
    __shared__ int   win[CELLS_];
    __shared__ float sM[28];

    const int i    = blockIdx.x;
    const int xcd  = i & 7;
    const int s    = i >> 3;
    const int b    = xcd + 8 * (s >= 12 ? 1 : 0);
    const int c12  = s % 12;
    const int m    = b * N_ + (c12 >> 1);
    const int rlo  = (c12 & 1) * HALF_;
    const int t    = threadIdx.x;

    if (t == 0) {
        float Vi[16];
        inv4(&view[b * 16], Vi);
        for (int k = 0; k < 12; ++k) sM[k] = Vi[k];
    } else if (t == 64) {
        float E2[4], PFC[3][4];
        cam_mats(&extr[m * 16], &intr[m * 9], E2, PFC);
        for (int ii = 0; ii < 3; ++ii)
            for (int jj = 0; jj < 4; ++jj) sM[12 + ii * 4 + jj] = PFC[ii][jj];
        for (int jj = 0; jj < 4; ++jj) sM[24 + jj] = E2[jj];
    }
    for (int k = t; k < CELLS_; k += 1024) win[k] = -1;
    __syncthreads();

    const float V0 = sM[0],  V1 = sM[1],  V2 = sM[2],  V3 = sM[3];
    const float V4 = sM[4],  V5 = sM[5],  V6 = sM[6],  V7 = sM[7];
    const float V8 = sM[8],  V9 = sM[9],  V10 = sM[10], V11 = sM[11];
    const float P00 = sM[12], P01 = sM[13], P02 = sM[14], P03 = sM[15];
    const float P10 = sM[16], P11 = sM[17], P12 = sM[18], P13 = sM[19];
    const float P20 = sM[20], P21 = sM[21], P22 = sM[22], P23 = sM[23];

    const float4* pcb = pc + (size_t)b * P_;
    int c0 = -1, c1 = -1, c2 = -1, c3 = -1;

#define PROC(PT, PIDX)                                                        \
    {                                                                         \
        float lx = rdot4(V0, V1, V2,  V3,  (PT).x, (PT).y, (PT).z);           \
        float ly = rdot4(V4, V5, V6,  V7,  (PT).x, (PT).y, (PT).z);           \
        float lz = rdot4(V8, V9, V10, V11, (PT).x, (PT).y, (PT).z);           \
        float px = rdot4(P00, P01, P02, P03, lx, ly, lz);                     \
        float py = rdot4(P10, P11, P12, P13, lx, ly, lz);                     \
        float pz = rdot4(P20, P21, P22, P23, lx, ly, lz);                     \
        float denom = fmaxf(pz, 1e-6f);                                       \
        float x_ = px / denom;                                                \
        float y_ = py / denom;                                                \
        int ym = (int)fminf(fmaxf(y_, 0.0f), (float)(H_ - 1));                \
        int xm = (int)fminf(fmaxf(x_, 0.0f), (float)(W_ - 1));                \
        bool is_c = (xm == 0 || xm == W_ - 1) && (ym == 0 || ym == H_ - 1);   \
        int code = ((ym != 0) << 1) | (xm != 0);                              \
        c0 = (is_c && code == 0) ? (PIDX) : c0;                               \
        c1 = (is_c && code == 1) ? (PIDX) : c1;                               \
        c2 = (is_c && code == 2) ? (PIDX) : c2;                               \
        c3 = (is_c && code == 3) ? (PIDX) : c3;                               \
        int rr = ym - rlo;                                                    \
        if (!is_c && (unsigned)rr < (unsigned)HALF_)                          \
            atomicMax(&win[rr * W_ + xm], (PIDX));                            \
    }

    for (int base = 0; base < PMAIN; base += 4 * 1024) {
        float4 q0 = pcb[base + t];
        float4 q1 = pcb[base + t + 1024];
        float4 q2 = pcb[base + t + 2 * 1024];
        float4 q3 = pcb[base + t + 3 * 1024];
        PROC(q0, base + t)
        PROC(q1, base + t + 1024)
        PROC(q2, base + t + 2 * 1024)
        PROC(q3, base + t + 3 * 1024)
    }
    if (t < PTAIL) {
        float4 q = pcb[PMAIN + t];
        PROC(q, PMAIN + t)
    }
#undef PROC

    for (int d = 32; d; d >>= 1) {
        c0 = max(c0, __shfl_xor(c0, d));
        c1 = max(c1, __shfl_xor(c1, d));
        c2 = max(c2, __shfl_xor(c2, d));
        c3 = max(c3, __shfl_xor(c3, d));
    }
    if ((t & 63) == 0) {
        if (rlo == 0) {
            if (c0 >= 0) atomicMax(&win[0],   c0);
            if (c1 >= 0) atomicMax(&win[199], c1);
        } else {
            if (c2 >= 0) atomicMax(&win[(H_ - 1 - rlo) * W_ + 0],   c2);
            if (c3 >= 0) atomicMax(&win[(H_ - 1 - rlo) * W_ + 199], c3);
        }
    }
    __syncthreads();

    const float bev_half = (float)bev_side_p[0] * 0.5f;
    const float clip_hi  = bev_half - 1.0f;
    const float E20 = sM[24], E21 = sM[25], E22 = sM[26], E23 = sM[27];
    const int base0 = (m * 2) * HW_ + rlo * W_;
    for (int r = t; r < CELLS_; r += 1024) {
        int wv = win[r];
        float depth = 0.0f, iluv = 0.0f;
        if (wv >= 0) {
            float4 pt = pcb[wv];
            float lx = rdot4(V0, V1, V2,  V3,  pt.x, pt.y, pt.z);
            float ly = rdot4(V4, V5, V6,  V7,  pt.x, pt.y, pt.z);
            float lz = rdot4(V8, V9, V10, V11, pt.x, pt.y, pt.z);
            float z  = rdot4(E20, E21, E22, E23, lx, ly, lz);
            float px = rdot4(P00, P01, P02, P03, lx, ly, lz);
            float py = rdot4(P10, P11, P12, P13, lx, ly, lz);
            float pz = rdot4(P20, P21, P22, P23, lx, ly, lz);
            float denom = fmaxf(pz, 1e-6f);
            float x_ = px / denom;
            float y_ = py / denom;
            bool valid = (x_ > -0.5f) && (x_ < (float)W_ - 0.5f) &&
                         (y_ > -0.5f) && (y_ < (float)H_ - 0.5f) && (z > 0.0f);
            if (valid) {
                float d = fminf(fmaxf(pz, 0.0f), clip_hi);
                depth = d / bev_half;
                float vi = fminf(fmaxf(pt.w, 0.0f), 255.0f);
                iluv = log1pf(vi) / 5.545177444479562f;
            }
        }
        out[base0 + r]       = depth;
        out[base0 + HW_ + r] = iluv;
    }
}

// ---------- launch ----------

extern "C" void kernel_launch(void* const* d_in, const int* in_sizes, int n_in,
                              void* d_out, int out_size, void* d_ws, size_t ws_size,
                              hipStream_t stream) {
    const float4* pc  = (const float4*)d_in[0];
    const float* extr = (const float*)d_in[1];
    const float* intr = (const float*)d_in[2];
    const float* view = (const float*)d_in[3];
    const int*   bev  = (const int*)d_in[4];
    float* out = (float*)d_out;

    if (ws_size >= WS_NEED) {
        char* ws = (char*)d_ws;
        float* wsf = (float*)(ws + WS_MAT_OFF);
        int* counts = (int*)(ws + WS_CNT_OFF);
        unsigned int* entries = (unsigned int*)(ws + WS_ENT_OFF);
        k_mats<<<dim3(1), dim3(128), 0, stream>>>(extr, intr, view, wsf);
        k_classify<<<dim3(B_, K1BLK), dim3(K1T), 0, stream>>>(
            pc, wsf, counts, entries);
        k_fin2<<<dim3(BSN_ * 2), dim3(1024), 0, stream>>>(
            pc, wsf, counts, entries, out, bev);
    } else {
        k_lidar_ilp<<<dim3(BSN_ * 2), dim3(1024), 0, stream>>>(
            pc, extr, intr, view, out, bev);
    }
}

// Round 14
// 44.096 us; speedup vs baseline: 1.5885x; 1.5885x over previous
//
#include <hip/hip_runtime.h>
#include <math.h>

#define B_    16
#define N_    6
#define P_    70000
#define H_    112
#define W_    200
#define HW_   (H_ * W_)
#define BSN_  (B_ * N_)
#define HALF_ 56                       // rows per block (H_/2)
#define CELLS_ (HALF_ * W_)            // 11200 cells, 44.8 KB LDS
#define THREADS_ 1024

// ---------- shared math helpers (identical codegen everywhere) ----------

__device__ __forceinline__ float rdot4(float r0, float r1, float r2, float r3,
                                       float x, float y, float z) {
    float s = r0 * x;
    s = fmaf(r1, y, s);
    s = fmaf(r2, z, s);
    return s + r3;
}

// 4x4 inverse via adjugate (matches jnp.linalg.inv bit-for-bit here — absmax
// 0.0 through rounds 1-13)
__device__ __forceinline__ void inv4(const float* m, float* o) {
    float inv[16];
    inv[0]  =  m[5]*m[10]*m[15] - m[5]*m[11]*m[14] - m[9]*m[6]*m[15] + m[9]*m[7]*m[14] + m[13]*m[6]*m[11] - m[13]*m[7]*m[10];
    inv[4]  = -m[4]*m[10]*m[15] + m[4]*m[11]*m[14] + m[8]*m[6]*m[15] - m[8]*m[7]*m[14] - m[12]*m[6]*m[11] + m[12]*m[7]*m[10];
    inv[8]  =  m[4]*m[9]*m[15]  - m[4]*m[11]*m[13] - m[8]*m[5]*m[15] + m[8]*m[7]*m[13] + m[12]*m[5]*m[11] - m[12]*m[7]*m[9];
    inv[12] = -m[4]*m[9]*m[14]  + m[4]*m[10]*m[13] + m[8]*m[5]*m[14] - m[8]*m[6]*m[13] - m[12]*m[5]*m[10] + m[12]*m[6]*m[9];
    inv[1]  = -m[1]*m[10]*m[15] + m[1]*m[11]*m[14] + m[9]*m[2]*m[15] - m[9]*m[3]*m[14] - m[13]*m[2]*m[11] + m[13]*m[3]*m[10];
    inv[5]  =  m[0]*m[10]*m[15] - m[0]*m[11]*m[14] - m[8]*m[2]*m[15] + m[8]*m[3]*m[14] + m[12]*m[2]*m[11] - m[12]*m[3]*m[10];
    inv[9]  = -m[0]*m[9]*m[15]  + m[0]*m[11]*m[13] + m[8]*m[1]*m[15] - m[8]*m[3]*m[13] - m[12]*m[1]*m[11] + m[12]*m[3]*m[9];
    inv[13] =  m[0]*m[9]*m[14]  - m[0]*m[10]*m[13] - m[8]*m[1]*m[14] + m[8]*m[2]*m[13] + m[12]*m[1]*m[10] - m[12]*m[2]*m[9];
    inv[2]  =  m[1]*m[6]*m[15]  - m[1]*m[7]*m[14]  - m[5]*m[2]*m[15] + m[5]*m[3]*m[14] + m[13]*m[2]*m[7]  - m[13]*m[3]*m[6];
    inv[6]  = -m[0]*m[6]*m[15]  + m[0]*m[7]*m[14]  + m[4]*m[2]*m[15] - m[4]*m[3]*m[14] - m[12]*m[2]*m[7]  + m[12]*m[3]*m[6];
    inv[10] =  m[0]*m[5]*m[15]  - m[0]*m[7]*m[13]  - m[4]*m[1]*m[15] + m[4]*m[3]*m[13] + m[12]*m[1]*m[7]  - m[12]*m[3]*m[5];
    inv[14] = -m[0]*m[5]*m[14]  + m[0]*m[6]*m[13]  + m[4]*m[1]*m[14] - m[4]*m[2]*m[13] - m[12]*m[1]*m[6]  + m[12]*m[2]*m[5];
    inv[3]  = -m[1]*m[6]*m[11]  + m[1]*m[7]*m[10]  + m[5]*m[2]*m[11] - m[5]*m[3]*m[10] - m[9]*m[2]*m[7]   + m[9]*m[3]*m[6];
    inv[7]  =  m[0]*m[6]*m[11]  - m[0]*m[7]*m[10]  - m[4]*m[2]*m[11] + m[4]*m[3]*m[10] + m[8]*m[2]*m[7]   - m[8]*m[3]*m[6];
    inv[11] = -m[0]*m[5]*m[11]  + m[0]*m[7]*m[9]   + m[4]*m[1]*m[11] - m[4]*m[3]*m[9]  - m[8]*m[1]*m[7]   + m[8]*m[3]*m[5];
    inv[15] =  m[0]*m[5]*m[10]  - m[0]*m[6]*m[9]   - m[4]*m[1]*m[10] + m[4]*m[2]*m[9]  + m[8]*m[1]*m[6]   - m[8]*m[2]*m[5];
    float det = m[0]*inv[0] + m[1]*inv[4] + m[2]*inv[8] + m[3]*inv[12];
    float rdet = 1.0f / det;
    for (int i = 0; i < 16; ++i) o[i] = inv[i] * rdet;
}

// Per-camera: Einv (rigid inverse) and PFC = scale_intrinsics4(K) @ Einv.
__device__ __forceinline__ void cam_mats(const float* Ein, const float* Kin,
                                         float E2[4], float PFC[3][4]) {
    float Einv[4][4];
    for (int i = 0; i < 3; ++i)
        for (int j = 0; j < 3; ++j)
            Einv[i][j] = Ein[j * 4 + i];          // R^T
    for (int i = 0; i < 3; ++i) {                  // -(R^T t), asc-j fma
        float s = Ein[0 * 4 + i] * Ein[0 * 4 + 3];
        s = fmaf(Ein[1 * 4 + i], Ein[1 * 4 + 3], s);
        s = fmaf(Ein[2 * 4 + i], Ein[2 * 4 + 3], s);
        Einv[i][3] = -s;
    }
    Einv[3][0] = Ein[12]; Einv[3][1] = Ein[13];
    Einv[3][2] = Ein[14]; Einv[3][3] = Ein[15];

    float K4[4][4] = {};
    K4[0][0] = Kin[0] * 0.25f;  K4[0][2] = Kin[2] * 0.25f;
    K4[1][1] = Kin[4] * 0.25f;  K4[1][2] = Kin[5] * 0.25f;
    K4[2][2] = 1.0f;            K4[3][3] = 1.0f;

    for (int i = 0; i < 3; ++i)
        for (int j = 0; j < 4; ++j) {
            float s = K4[i][0] * Einv[0][j];
            s = fmaf(K4[i][1], Einv[1][j], s);
            s = fmaf(K4[i][2], Einv[2][j], s);
            s = fmaf(K4[i][3], Einv[3][j], s);
            PFC[i][j] = s;
        }
    for (int j = 0; j < 4; ++j) E2[j] = Einv[2][j];
}

// ---------- fused kernel: one block per (camera m, row-half) ----------
// R8 structure (proven absmax 0.0, best dur 46.7us) with the point loop
// replaced by R12-verified conservative screens:
//   px <= 0.99*denom => x_<1      => xm==0  ;  px >= 201*denom => x_>200.9 => xm==199
//   py <= 0.99*denom => ym==0     ;  py >= 113*denom => y_>112.9 => ym==111
// (denom>0 always; fp32 div rounding << margins, implication exact.)
// Certain-corner pairs -> per-lane register max (p ascending => assign=max).
// Certain corners of the OTHER half -> skip (owned by the other block).
// Uncertain pairs (~1%) -> exact reference divide/clip + LDS atomicMax.

__global__ __launch_bounds__(THREADS_) void k_lidar_scr(
        const float4* __restrict__ pc, const float* __restrict__ extr,
        const float* __restrict__ intr, const float* __restrict__ view,
        float* __restrict__ out, const int* __restrict__ bev_side_p) {
    __shared__ int   win[CELLS_];      // 44.8 KB
    __shared__ float sM[28];           // 0..11 Vinv, 12..23 PFC, 24..27 E2

    // XCD swizzle: co-locate all 12 blocks of one batch on one XCD.
    const int i    = blockIdx.x;       // 0..191
    const int xcd  = i & 7;
    const int s    = i >> 3;           // 0..23
    const int b    = xcd + 8 * (s >= 12 ? 1 : 0);
    const int c12  = s % 12;
    const int m    = b * N_ + (c12 >> 1);
    const int half = c12 & 1;
    const int rlo  = half * HALF_;
    const int t    = threadIdx.x;

    if (t == 0) {                      // wave 0: Vinv
        float Vi[16];
        inv4(&view[b * 16], Vi);
        for (int k = 0; k < 12; ++k) sM[k] = Vi[k];
    } else if (t == 64) {              // wave 1: this camera
        float E2[4], PFC[3][4];
        cam_mats(&extr[m * 16], &intr[m * 9], E2, PFC);
        for (int ii = 0; ii < 3; ++ii)
            for (int jj = 0; jj < 4; ++jj) sM[12 + ii * 4 + jj] = PFC[ii][jj];
        for (int jj = 0; jj < 4; ++jj) sM[24 + jj] = E2[jj];
    }
    for (int k = t; k < CELLS_; k += THREADS_) win[k] = -1;
    __syncthreads();

    // hoist matrices to registers
    const float V0 = sM[0],  V1 = sM[1],  V2 = sM[2],  V3 = sM[3];
    const float V4 = sM[4],  V5 = sM[5],  V6 = sM[6],  V7 = sM[7];
    const float V8 = sM[8],  V9 = sM[9],  V10 = sM[10], V11 = sM[11];
    const float P00 = sM[12], P01 = sM[13], P02 = sM[14], P03 = sM[15];
    const float P10 = sM[16], P11 = sM[17], P12 = sM[18], P13 = sM[19];
    const float P20 = sM[20], P21 = sM[21], P22 = sM[22], P23 = sM[23];

    const float4* pcb = pc + (size_t)b * P_;
    int cA = -1, cB = -1;              // this half's two corner winners

    // ---- Phase A: screened scan ----
    for (int p = t; p < P_; p += THREADS_) {      // p ascending per thread
        float4 pt = pcb[p];
        float lx = rdot4(V0, V1, V2,  V3,  pt.x, pt.y, pt.z);
        float ly = rdot4(V4, V5, V6,  V7,  pt.x, pt.y, pt.z);
        float lz = rdot4(V8, V9, V10, V11, pt.x, pt.y, pt.z);
        float px = rdot4(P00, P01, P02, P03, lx, ly, lz);
        float py = rdot4(P10, P11, P12, P13, lx, ly, lz);
        float pz = rdot4(P20, P21, P22, P23, lx, ly, lz);
        float denom = fmaxf(pz, 1e-6f);
        bool x0 = (px <= 0.99f  * denom);
        bool x1 = (px >= 201.0f * denom);
        bool y0 = (py <= 0.99f  * denom);
        bool y1 = (py >= 113.0f * denom);
        bool yh = half ? y1 : y0;                 // own-half certain y
        cA = (x0 & yh) ? p : cA;                  // (own-half, x=0) corner
        cB = (x1 & yh) ? p : cB;                  // (own-half, x=199) corner
        if (!((x0 | x1) & (y0 | y1))) {           // uncertain -> exact path
            float x_ = px / denom;                // reference sequence
            float y_ = py / denom;
            int ym = (int)fminf(fmaxf(y_, 0.0f), (float)(H_ - 1));
            int xm = (int)fminf(fmaxf(x_, 0.0f), (float)(W_ - 1));
            bool is_c = (xm == 0 || xm == W_ - 1) && (ym == 0 || ym == H_ - 1);
            int rr = ym - rlo;
            if ((unsigned)rr < (unsigned)HALF_) {
                if (is_c) {                       // computed corner hit
                    bool right = (xm != 0);
                    cA = (!right) ? max(cA, p) : cA;
                    cB = ( right) ? max(cB, p) : cB;
                } else {
                    atomicMax(&win[rr * W_ + xm], p);
                }
            }
        }
    }
    // wave-reduce corner maxima, then one LDS atomic per wave per corner
    for (int d = 32; d; d >>= 1) {
        cA = max(cA, __shfl_xor(cA, d));
        cB = max(cB, __shfl_xor(cB, d));
    }
    if ((t & 63) == 0) {
        int cell0 = half ? (HALF_ - 1) * W_ : 0;
        if (cA >= 0) atomicMax(&win[cell0],          cA);
        if (cB >= 0) atomicMax(&win[cell0 + W_ - 1], cB);
    }
    __syncthreads();

    // ---- Phase B: finalize (bit-exact path, proven rounds 1-13) ----
    const float bev_half = (float)bev_side_p[0] * 0.5f;   // 100.0
    const float clip_hi  = bev_half - 1.0f;               // 99.0
    const float E20 = sM[24], E21 = sM[25], E22 = sM[26], E23 = sM[27];
    const int base0 = (m * 2) * HW_ + rlo * W_;
    for (int r = t; r < CELLS_; r += THREADS_) {
        int w = win[r];
        float depth = 0.0f, iluv = 0.0f;
        if (w >= 0) {
            float4 pt = pcb[w];
            float lx = rdot4(V0, V1, V2,  V3,  pt.x, pt.y, pt.z);
            float ly = rdot4(V4, V5, V6,  V7,  pt.x, pt.y, pt.z);
            float lz = rdot4(V8, V9, V10, V11, pt.x, pt.y, pt.z);
            float z  = rdot4(E20, E21, E22, E23, lx, ly, lz);
            float px = rdot4(P00, P01, P02, P03, lx, ly, lz);
            float py = rdot4(P10, P11, P12, P13, lx, ly, lz);
            float pz = rdot4(P20, P21, P22, P23, lx, ly, lz);
            float denom = fmaxf(pz, 1e-6f);
            float x_ = px / denom;
            float y_ = py / denom;
            bool valid = (x_ > -0.5f) && (x_ < (float)W_ - 0.5f) &&
                         (y_ > -0.5f) && (y_ < (float)H_ - 0.5f) && (z > 0.0f);
            if (valid) {
                float d = fminf(fmaxf(pz, 0.0f), clip_hi);     // clip(normalizer,0,99)
                depth = d / bev_half;                           // /100
                float vi = fminf(fmaxf(pt.w, 0.0f), 255.0f);    // clip(ilu,0,255)
                iluv = log1pf(vi) / 5.545177444479562f;         // /log(256) as f32
            }
        }
        out[base0 + r]       = depth;
        out[base0 + HW_ + r] = iluv;
    }
}

// ---------- launch ----------

extern "C" void kernel_launch(void* const* d_in, const int* in_sizes, int n_in,
                              void* d_out, int out_size, void* d_ws, size_t ws_size,
                              hipStream_t stream) {
    const float4* pc  = (const float4*)d_in[0];
    const float* extr = (const float*)d_in[1];
    const float* intr = (const float*)d_in[2];
    const float* view = (const float*)d_in[3];
    const int*   bev  = (const int*)d_in[4];
    float* out = (float*)d_out;

    k_lidar_scr<<<dim3(BSN_ * 2), dim3(THREADS_), 0, stream>>>(
        pc, extr, intr, view, out, bev);
}

// Round 15
// 42.592 us; speedup vs baseline: 1.6446x; 1.0353x over previous
//
#include <hip/hip_runtime.h>
#include <math.h>

#define B_    16
#define N_    6
#define P_    70000
#define H_    112
#define W_    200
#define HW_   (H_ * W_)
#define BSN_  (B_ * N_)
#define HALF_ 56                       // rows per block (H_/2)
#define CELLS_ (HALF_ * W_)            // 11200 cells, 44.8 KB LDS
#define THREADS_ 1024
#define GRP   (4 * THREADS_)           // 4096 points per pipeline group
#define PMAIN 69632                    // 17 * 4096
#define PTAIL (P_ - PMAIN)             // 368

// ---------- shared math helpers (identical codegen everywhere) ----------

__device__ __forceinline__ float rdot4(float r0, float r1, float r2, float r3,
                                       float x, float y, float z) {
    float s = r0 * x;
    s = fmaf(r1, y, s);
    s = fmaf(r2, z, s);
    return s + r3;
}

// 4x4 inverse via adjugate (matches jnp.linalg.inv bit-for-bit here — absmax
// 0.0 through rounds 1-14)
__device__ __forceinline__ void inv4(const float* m, float* o) {
    float inv[16];
    inv[0]  =  m[5]*m[10]*m[15] - m[5]*m[11]*m[14] - m[9]*m[6]*m[15] + m[9]*m[7]*m[14] + m[13]*m[6]*m[11] - m[13]*m[7]*m[10];
    inv[4]  = -m[4]*m[10]*m[15] + m[4]*m[11]*m[14] + m[8]*m[6]*m[15] - m[8]*m[7]*m[14] - m[12]*m[6]*m[11] + m[12]*m[7]*m[10];
    inv[8]  =  m[4]*m[9]*m[15]  - m[4]*m[11]*m[13] - m[8]*m[5]*m[15] + m[8]*m[7]*m[13] + m[12]*m[5]*m[11] - m[12]*m[7]*m[9];
    inv[12] = -m[4]*m[9]*m[14]  + m[4]*m[10]*m[13] + m[8]*m[5]*m[14] - m[8]*m[6]*m[13] - m[12]*m[5]*m[10] + m[12]*m[6]*m[9];
    inv[1]  = -m[1]*m[10]*m[15] + m[1]*m[11]*m[14] + m[9]*m[2]*m[15] - m[9]*m[3]*m[14] - m[13]*m[2]*m[11] + m[13]*m[3]*m[10];
    inv[5]  =  m[0]*m[10]*m[15] - m[0]*m[11]*m[14] - m[8]*m[2]*m[15] + m[8]*m[3]*m[14] + m[12]*m[2]*m[11] - m[12]*m[3]*m[10];
    inv[9]  = -m[0]*m[9]*m[15]  + m[0]*m[11]*m[13] + m[8]*m[1]*m[15] - m[8]*m[3]*m[13] - m[12]*m[1]*m[11] + m[12]*m[3]*m[9];
    inv[13] =  m[0]*m[9]*m[14]  - m[0]*m[10]*m[13] - m[8]*m[1]*m[14] + m[8]*m[2]*m[13] + m[12]*m[1]*m[10] - m[12]*m[2]*m[9];
    inv[2]  =  m[1]*m[6]*m[15]  - m[1]*m[7]*m[14]  - m[5]*m[2]*m[15] + m[5]*m[3]*m[14] + m[13]*m[2]*m[7]  - m[13]*m[3]*m[6];
    inv[6]  = -m[0]*m[6]*m[15]  + m[0]*m[7]*m[14]  + m[4]*m[2]*m[15] - m[4]*m[3]*m[14] - m[12]*m[2]*m[7]  + m[12]*m[3]*m[6];
    inv[10] =  m[0]*m[5]*m[15]  - m[0]*m[7]*m[13]  - m[4]*m[1]*m[15] + m[4]*m[3]*m[13] + m[12]*m[1]*m[7]  - m[12]*m[3]*m[5];
    inv[14] = -m[0]*m[5]*m[14]  + m[0]*m[6]*m[13]  + m[4]*m[1]*m[14] - m[4]*m[2]*m[13] - m[12]*m[1]*m[6]  + m[12]*m[2]*m[5];
    inv[3]  = -m[1]*m[6]*m[11]  + m[1]*m[7]*m[10]  + m[5]*m[2]*m[11] - m[5]*m[3]*m[10] - m[9]*m[2]*m[7]   + m[9]*m[3]*m[6];
    inv[7]  =  m[0]*m[6]*m[11]  - m[0]*m[7]*m[10]  - m[4]*m[2]*m[11] + m[4]*m[3]*m[10] + m[8]*m[2]*m[7]   - m[8]*m[3]*m[6];
    inv[11] = -m[0]*m[5]*m[11]  + m[0]*m[7]*m[9]   + m[4]*m[1]*m[11] - m[4]*m[3]*m[9]  - m[8]*m[1]*m[7]   + m[8]*m[3]*m[5];
    inv[15] =  m[0]*m[5]*m[10]  - m[0]*m[6]*m[9]   - m[4]*m[1]*m[10] + m[4]*m[2]*m[9]  + m[8]*m[1]*m[6]   - m[8]*m[2]*m[5];
    float det = m[0]*inv[0] + m[1]*inv[4] + m[2]*inv[8] + m[3]*inv[12];
    float rdet = 1.0f / det;
    for (int i = 0; i < 16; ++i) o[i] = inv[i] * rdet;
}

// Per-camera: Einv (rigid inverse) and PFC = scale_intrinsics4(K) @ Einv.
__device__ __forceinline__ void cam_mats(const float* Ein, const float* Kin,
                                         float E2[4], float PFC[3][4]) {
    float Einv[4][4];
    for (int i = 0; i < 3; ++i)
        for (int j = 0; j < 3; ++j)
            Einv[i][j] = Ein[j * 4 + i];          // R^T
    for (int i = 0; i < 3; ++i) {                  // -(R^T t), asc-j fma
        float s = Ein[0 * 4 + i] * Ein[0 * 4 + 3];
        s = fmaf(Ein[1 * 4 + i], Ein[1 * 4 + 3], s);
        s = fmaf(Ein[2 * 4 + i], Ein[2 * 4 + 3], s);
        Einv[i][3] = -s;
    }
    Einv[3][0] = Ein[12]; Einv[3][1] = Ein[13];
    Einv[3][2] = Ein[14]; Einv[3][3] = Ein[15];

    float K4[4][4] = {};
    K4[0][0] = Kin[0] * 0.25f;  K4[0][2] = Kin[2] * 0.25f;
    K4[1][1] = Kin[4] * 0.25f;  K4[1][2] = Kin[5] * 0.25f;
    K4[2][2] = 1.0f;            K4[3][3] = 1.0f;

    for (int i = 0; i < 3; ++i)
        for (int j = 0; j < 4; ++j) {
            float s = K4[i][0] * Einv[0][j];
            s = fmaf(K4[i][1], Einv[1][j], s);
            s = fmaf(K4[i][2], Einv[2][j], s);
            s = fmaf(K4[i][3], Einv[3][j], s);
            PFC[i][j] = s;
        }
    for (int j = 0; j < 4; ++j) E2[j] = Einv[2][j];
}

// ---------- fused kernel: one block per (camera m, row-half) ----------
// R14 (screens, 44.1us, absmax 0.0) + depth-4 software-pipelined point loop:
// group g+1's loads issue BEFORE group g's compute; sched_barrier(0) pins
// them there so the compiler must keep them live (R8's ILP4 was re-serialized
// at VGPR=32 -> ~1000cyc serial load->use chain per iteration was the floor).

__global__ __launch_bounds__(THREADS_) void k_lidar_pipe(
        const float4* __restrict__ pc, const float* __restrict__ extr,
        const float* __restrict__ intr, const float* __restrict__ view,
        float* __restrict__ out, const int* __restrict__ bev_side_p) {
    __shared__ int   win[CELLS_];      // 44.8 KB
    __shared__ float sM[28];           // 0..11 Vinv, 12..23 PFC, 24..27 E2

    // XCD swizzle: co-locate all 12 blocks of one batch on one XCD.
    const int i    = blockIdx.x;       // 0..191
    const int xcd  = i & 7;
    const int s    = i >> 3;           // 0..23
    const int b    = xcd + 8 * (s >= 12 ? 1 : 0);
    const int c12  = s % 12;
    const int m    = b * N_ + (c12 >> 1);
    const int half = c12 & 1;
    const int rlo  = half * HALF_;
    const int t    = threadIdx.x;

    if (t == 0) {                      // wave 0: Vinv
        float Vi[16];
        inv4(&view[b * 16], Vi);
        for (int k = 0; k < 12; ++k) sM[k] = Vi[k];
    } else if (t == 64) {              // wave 1: this camera
        float E2[4], PFC[3][4];
        cam_mats(&extr[m * 16], &intr[m * 9], E2, PFC);
        for (int ii = 0; ii < 3; ++ii)
            for (int jj = 0; jj < 4; ++jj) sM[12 + ii * 4 + jj] = PFC[ii][jj];
        for (int jj = 0; jj < 4; ++jj) sM[24 + jj] = E2[jj];
    }
    for (int k = t; k < CELLS_; k += THREADS_) win[k] = -1;
    __syncthreads();

    // hoist matrices to registers
    const float V0 = sM[0],  V1 = sM[1],  V2 = sM[2],  V3 = sM[3];
    const float V4 = sM[4],  V5 = sM[5],  V6 = sM[6],  V7 = sM[7];
    const float V8 = sM[8],  V9 = sM[9],  V10 = sM[10], V11 = sM[11];
    const float P00 = sM[12], P01 = sM[13], P02 = sM[14], P03 = sM[15];
    const float P10 = sM[16], P11 = sM[17], P12 = sM[18], P13 = sM[19];
    const float P20 = sM[20], P21 = sM[21], P22 = sM[22], P23 = sM[23];

    const float4* pcb = pc + (size_t)b * P_;
    int cA = -1, cB = -1;              // this half's two corner winners

    // per-point phase-A body: R12/R14-verified conservative screens.
    //   px <= 0.99*denom => xm==0 ; px >= 201*denom => xm==199 (same y: 113)
    // Certain own-half corners -> register max (p ascending => assign=max).
    // Uncertain (~1%) -> exact reference divide/clip + LDS atomicMax.
#define PROC(PT, PIDX)                                                        \
    {                                                                         \
        float lx = rdot4(V0, V1, V2,  V3,  (PT).x, (PT).y, (PT).z);           \
        float ly = rdot4(V4, V5, V6,  V7,  (PT).x, (PT).y, (PT).z);           \
        float lz = rdot4(V8, V9, V10, V11, (PT).x, (PT).y, (PT).z);           \
        float px = rdot4(P00, P01, P02, P03, lx, ly, lz);                     \
        float py = rdot4(P10, P11, P12, P13, lx, ly, lz);                     \
        float pz = rdot4(P20, P21, P22, P23, lx, ly, lz);                     \
        float denom = fmaxf(pz, 1e-6f);                                       \
        bool x0 = (px <= 0.99f  * denom);                                     \
        bool x1 = (px >= 201.0f * denom);                                     \
        bool y0 = (py <= 0.99f  * denom);                                     \
        bool y1 = (py >= 113.0f * denom);                                     \
        bool yh = half ? y1 : y0;                                             \
        cA = (x0 & yh) ? (PIDX) : cA;                                         \
        cB = (x1 & yh) ? (PIDX) : cB;                                         \
        if (!((x0 | x1) & (y0 | y1))) {                                       \
            float x_ = px / denom;                                            \
            float y_ = py / denom;                                            \
            int ym = (int)fminf(fmaxf(y_, 0.0f), (float)(H_ - 1));            \
            int xm = (int)fminf(fmaxf(x_, 0.0f), (float)(W_ - 1));            \
            bool is_c = (xm == 0 || xm == W_ - 1) &&                          \
                        (ym == 0 || ym == H_ - 1);                            \
            int rr = ym - rlo;                                                \
            if ((unsigned)rr < (unsigned)HALF_) {                             \
                if (is_c) {                                                   \
                    bool right = (xm != 0);                                   \
                    cA = (!right) ? max(cA, (PIDX)) : cA;                     \
                    cB = ( right) ? max(cB, (PIDX)) : cB;                     \
                } else {                                                      \
                    atomicMax(&win[rr * W_ + xm], (PIDX));                    \
                }                                                             \
            }                                                                 \
        }                                                                     \
    }

    // ---- Phase A: depth-4 software pipeline over 17 groups of 4096 ----
    float4 q0 = pcb[t];
    float4 q1 = pcb[t + THREADS_];
    float4 q2 = pcb[t + 2 * THREADS_];
    float4 q3 = pcb[t + 3 * THREADS_];
    for (int gbase = 0; gbase < PMAIN - GRP; gbase += GRP) {
        // issue next group's loads FIRST; pin them above this group's compute
        float4 n0 = pcb[gbase + GRP + t];
        float4 n1 = pcb[gbase + GRP + t + THREADS_];
        float4 n2 = pcb[gbase + GRP + t + 2 * THREADS_];
        float4 n3 = pcb[gbase + GRP + t + 3 * THREADS_];
        __builtin_amdgcn_sched_barrier(0);
        PROC(q0, gbase + t)
        PROC(q1, gbase + t + THREADS_)
        PROC(q2, gbase + t + 2 * THREADS_)
        PROC(q3, gbase + t + 3 * THREADS_)
        q0 = n0; q1 = n1; q2 = n2; q3 = n3;
    }
    {   // last full group (gbase = PMAIN-GRP = 65536)
        const int gbase = PMAIN - GRP;
        PROC(q0, gbase + t)
        PROC(q1, gbase + t + THREADS_)
        PROC(q2, gbase + t + 2 * THREADS_)
        PROC(q3, gbase + t + 3 * THREADS_)
    }
    if (t < PTAIL) {                   // tail: points 69632..69999 (ascending)
        float4 q = pcb[PMAIN + t];
        PROC(q, PMAIN + t)
    }
#undef PROC

    // wave-reduce corner maxima, then one LDS atomic per wave per corner
    for (int d = 32; d; d >>= 1) {
        cA = max(cA, __shfl_xor(cA, d));
        cB = max(cB, __shfl_xor(cB, d));
    }
    if ((t & 63) == 0) {
        int cell0 = half ? (HALF_ - 1) * W_ : 0;
        if (cA >= 0) atomicMax(&win[cell0],          cA);
        if (cB >= 0) atomicMax(&win[cell0 + W_ - 1], cB);
    }
    __syncthreads();

    // ---- Phase B: finalize (bit-exact path, proven rounds 1-14) ----
    const float bev_half = (float)bev_side_p[0] * 0.5f;   // 100.0
    const float clip_hi  = bev_half - 1.0f;               // 99.0
    const float E20 = sM[24], E21 = sM[25], E22 = sM[26], E23 = sM[27];
    const int base0 = (m * 2) * HW_ + rlo * W_;
    for (int r = t; r < CELLS_; r += THREADS_) {
        int w = win[r];
        float depth = 0.0f, iluv = 0.0f;
        if (w >= 0) {
            float4 pt = pcb[w];
            float lx = rdot4(V0, V1, V2,  V3,  pt.x, pt.y, pt.z);
            float ly = rdot4(V4, V5, V6,  V7,  pt.x, pt.y, pt.z);
            float lz = rdot4(V8, V9, V10, V11, pt.x, pt.y, pt.z);
            float z  = rdot4(E20, E21, E22, E23, lx, ly, lz);
            float px = rdot4(P00, P01, P02, P03, lx, ly, lz);
            float py = rdot4(P10, P11, P12, P13, lx, ly, lz);
            float pz = rdot4(P20, P21, P22, P23, lx, ly, lz);
            float denom = fmaxf(pz, 1e-6f);
            float x_ = px / denom;
            float y_ = py / denom;
            bool valid = (x_ > -0.5f) && (x_ < (float)W_ - 0.5f) &&
                         (y_ > -0.5f) && (y_ < (float)H_ - 0.5f) && (z > 0.0f);
            if (valid) {
                float d = fminf(fmaxf(pz, 0.0f), clip_hi);     // clip(normalizer,0,99)
                depth = d / bev_half;                           // /100
                float vi = fminf(fmaxf(pt.w, 0.0f), 255.0f);    // clip(ilu,0,255)
                iluv = log1pf(vi) / 5.545177444479562f;         // /log(256) as f32
            }
        }
        out[base0 + r]       = depth;
        out[base0 + HW_ + r] = iluv;
    }
}

// ---------- launch ----------

extern "C" void kernel_launch(void* const* d_in, const int* in_sizes, int n_in,
                              void* d_out, int out_size, void* d_ws, size_t ws_size,
                              hipStream_t stream) {
    const float4* pc  = (const float4*)d_in[0];
    const float* extr = (const float*)d_in[1];
    const float* intr = (const float*)d_in[2];
    const float* view = (const float*)d_in[3];
    const int*   bev  = (const int*)d_in[4];
    float* out = (float*)d_out;

    k_lidar_pipe<<<dim3(BSN_ * 2), dim3(THREADS_), 0, stream>>>(
        pc, extr, intr, view, out, bev);
}